// Round 3
// baseline (1375.280 us; speedup 1.0000x reference)
//
#include <hip/hip_runtime.h>
#include <hip/hip_cooperative_groups.h>
#include <math.h>

namespace cg = cooperative_groups;

// ---------------------------------------------------------------------------
// MPConv round 5: ONE cooperative kernel (launch overhead was ~60-75us/launch).
//   phase0: zero counts/out/cursor, prep W->bf16, x->bf16
//   phase1: hist(dst)        phase2: parallel exclusive scan (3 sub-phases)
//   phase3: build perm       phase4: main MPConv, dynamic 64-edge wave-tiles
// grid.sync() + __threadfence() between phases (cross-XCD visibility).
// Fallback on cooperative-launch error: round-2 multi-kernel sequence.
// ---------------------------------------------------------------------------

using short8 = __attribute__((ext_vector_type(8))) short;
using f32x4  = __attribute__((ext_vector_type(4))) float;

#define LDH 72        // bf16 H-tile stride (64+8)
#define WREG 9472     // per-wave LDS: max(64*72*2, 32*66*4)=9216 + 64*4 dstL, aligned
#define SMEM_BYTES (4 * WREG)   // 37,888
#define MAXBLK 4096

static __device__ __forceinline__ short f2bf(float f) {
    unsigned u = __float_as_uint(f);
    u += 0x7FFFu + ((u >> 16) & 1u);        // round-to-nearest-even
    return (short)(u >> 16);
}

static __device__ __forceinline__ short8 pack8(float4 a, float4 b) {
    short8 r;
    r[0] = f2bf(a.x); r[1] = f2bf(a.y); r[2] = f2bf(a.z); r[3] = f2bf(a.w);
    r[4] = f2bf(b.x); r[5] = f2bf(b.y); r[6] = f2bf(b.z); r[7] = f2bf(b.w);
    return r;
}

// ======================= fused cooperative kernel ==========================
__global__ __launch_bounds__(256) void mpconv_fused(
    const float* __restrict__ x,      // [N,64]
    const int*   __restrict__ ei,     // [2,E]
    const float* __restrict__ ea,     // [E,32]
    const float* __restrict__ W1,     // [160,64]
    const float* __restrict__ W2,     // [64,64]
    const float* __restrict__ b1,
    const float* __restrict__ gam,
    const float* __restrict__ bet,
    const float* __restrict__ b2,
    short* __restrict__ Wt1,          // [64][160] bf16
    short* __restrict__ Wt2,          // [64][64]  bf16
    short* __restrict__ xbf,          // [N][64]   bf16
    int*   __restrict__ counts,       // [N]
    int*   __restrict__ offs,         // [N]
    int*   __restrict__ bsum,         // [MAXBLK]
    int*   __restrict__ boff,         // [MAXBLK]
    int*   __restrict__ perm,         // [E]
    int*   __restrict__ cursor,       // [1]
    float* __restrict__ out,          // [N,64]
    int E, int N, int out_elems)
{
    __shared__ __align__(16) char smem[SMEM_BYTES];
    cg::grid_group grid = cg::this_grid();
    const int tid = blockIdx.x * 256 + threadIdx.x;
    const int TT  = gridDim.x * 256;

#define GBAR() do { __threadfence(); grid.sync(); __threadfence(); } while (0)

    // ---------------- phase 0: zero + weight/x prep ---------------------
    for (int i = tid; i < N; i += TT) counts[i] = 0;
    {
        int nf4 = out_elems >> 2;
        float4 z = make_float4(0.f, 0.f, 0.f, 0.f);
        for (int i = tid; i < nf4; i += TT) ((float4*)out)[i] = z;
        for (int i = (nf4 << 2) + tid; i < out_elems; i += TT) out[i] = 0.f;
    }
    if (tid == 0) *cursor = 0;
    for (int t = tid; t < 160 * 64; t += TT) {
        int k = t / 64, n = t % 64;
        Wt1[n * 160 + k] = f2bf(W1[t]);
    }
    for (int t = tid; t < 64 * 64; t += TT) {
        int k = t / 64, n = t % 64;
        Wt2[n * 64 + k] = f2bf(W2[t]);
    }
    {
        const float4* xf4 = (const float4*)x;
        for (int t = tid; t < N * 8; t += TT) {
            float4 a = xf4[2 * t];
            float4 b = xf4[2 * t + 1];
            ((short8*)xbf)[t] = pack8(a, b);
        }
    }
    GBAR();

    // ---------------- phase 1: histogram of dst -------------------------
    for (int e = tid; e < E; e += TT) atomicAdd(&counts[ei[E + e]], 1);
    GBAR();

    // ---------------- phase 2a: per-block chunk sums ---------------------
    const int NBLK = gridDim.x;
    const int CH = (N + NBLK - 1) / NBLK;
    int* sc = (int*)smem;
    {
        int base = blockIdx.x * CH;
        int s = 0;
        for (int o = threadIdx.x; o < CH; o += 256) {
            int i = base + o;
            if (i < N) s += counts[i];
        }
        sc[threadIdx.x] = s;
        __syncthreads();
        for (int d = 1; d < 256; d <<= 1) {
            int u = (threadIdx.x >= (unsigned)d) ? sc[threadIdx.x - d] : 0;
            __syncthreads();
            sc[threadIdx.x] += u;
            __syncthreads();
        }
        if (threadIdx.x == 255) bsum[blockIdx.x] = sc[255];
    }
    GBAR();

    // ---------------- phase 2b: block 0 scans bsum -> boff ---------------
    if (blockIdx.x == 0) {
        int per = (NBLK + 255) / 256;            // <= 16 (NBLK <= 4096)
        int lex[16];
        int lsum = 0;
#pragma unroll
        for (int i2 = 0; i2 < 16; i2++) {
            int idx = threadIdx.x * per + i2;
            int v = (i2 < per && idx < NBLK) ? bsum[idx] : 0;
            lex[i2] = lsum;
            lsum += v;
        }
        sc[threadIdx.x] = lsum;
        __syncthreads();
        for (int d = 1; d < 256; d <<= 1) {
            int u = (threadIdx.x >= (unsigned)d) ? sc[threadIdx.x - d] : 0;
            __syncthreads();
            sc[threadIdx.x] += u;
            __syncthreads();
        }
        int texcl = sc[threadIdx.x] - lsum;
#pragma unroll
        for (int i2 = 0; i2 < 16; i2++) {
            int idx = threadIdx.x * per + i2;
            if (i2 < per && idx < NBLK) boff[idx] = texcl + lex[i2];
        }
    }
    GBAR();

    // ---------------- phase 2c: exclusive offs within chunk --------------
    {
        int base = blockIdx.x * CH;
        int running = boff[blockIdx.x];
        for (int o = 0; o < CH; o += 256) {
            int li = o + (int)threadIdx.x;
            int i = base + li;
            int v = (li < CH && i < N) ? counts[i] : 0;
            sc[threadIdx.x] = v;
            __syncthreads();
            for (int d = 1; d < 256; d <<= 1) {
                int u = (threadIdx.x >= (unsigned)d) ? sc[threadIdx.x - d] : 0;
                __syncthreads();
                sc[threadIdx.x] += u;
                __syncthreads();
            }
            if (li < CH && i < N) offs[i] = running + sc[threadIdx.x] - v;
            running += sc[255];
            __syncthreads();
        }
    }
    GBAR();

    // ---------------- phase 3: build dst-sorted permutation --------------
    for (int e = tid; e < E; e += TT) {
        int dst = ei[E + e];
        int pos = atomicAdd(&offs[dst], 1);
        perm[pos] = e;
    }
    GBAR();

    // ---------------- phase 4: main MPConv, dynamic wave-tiles -----------
    const int wave = threadIdx.x >> 6;
    const int lane = threadIdx.x & 63;
    const int g    = lane >> 4;
    const int col  = lane & 15;

    char* wbase = smem + wave * WREG;
    short (*Hl)[LDH] = (short (*)[LDH])wbase;   // [64][72] bf16
    float (*Hf)[66]  = (float (*)[66])wbase;    // [32][66] f32 (aliases Hl)
    int*  dstL       = (int*)(wbase + 9216);    // [64]

    float b1c[4], gc[4], bc[4], b2c[4];
#pragma unroll
    for (int nt = 0; nt < 4; nt++) {
        int c = col + 16 * nt;
        b1c[nt] = b1[c]; gc[nt] = gam[c]; bc[nt] = bet[c]; b2c[nt] = b2[c];
    }

    const int ntilesW = (E + 63) / 64;

    for (;;) {
        int t0 = 0;
        if (lane == 0) t0 = atomicAdd(cursor, 1);
        int tile = __shfl(t0, 0);
        if (tile >= ntilesW) break;
        const int eb = tile * 64;

        int aedge[4], ii[4], jj[4];
#pragma unroll
        for (int mt = 0; mt < 4; mt++) {
            int ep = eb + mt * 16 + col;
            bool v = (ep < E);
            int epc = v ? ep : (E - 1);
            int e = perm[epc];
            aedge[mt] = e;
            ii[mt] = ei[e];
            jj[mt] = ei[E + e];
            if (g == 0) dstL[mt * 16 + col] = v ? jj[mt] : -1;
        }

        // ---- GEMM1 ----
        f32x4 acc[4][4];
#pragma unroll
        for (int mt = 0; mt < 4; mt++)
#pragma unroll
            for (int nt = 0; nt < 4; nt++)
                acc[mt][nt] = (f32x4){0.f, 0.f, 0.f, 0.f};

#pragma unroll
        for (int ks = 0; ks < 5; ks++) {
            const int k0 = ks * 32;
            const int kk = k0 + g * 8;

            short8 afrag[4];
#pragma unroll
            for (int mt = 0; mt < 4; mt++) {
                if (k0 < 64) {
                    afrag[mt] = *(const short8*)(xbf + (size_t)ii[mt] * 64 + kk);
                } else if (k0 < 128) {
                    afrag[mt] = *(const short8*)(xbf + (size_t)jj[mt] * 64 + (kk - 64));
                } else {
                    const float* s = ea + (size_t)aedge[mt] * 32 + (kk - 128);
                    float4 a = *(const float4*)s;
                    float4 b = *(const float4*)(s + 4);
                    afrag[mt] = pack8(a, b);
                }
            }
            short8 bfrag[4];
#pragma unroll
            for (int nt = 0; nt < 4; nt++)
                bfrag[nt] = *(const short8*)(Wt1 + (size_t)(col + 16 * nt) * 160 + kk);

#pragma unroll
            for (int mt = 0; mt < 4; mt++)
#pragma unroll
                for (int nt = 0; nt < 4; nt++)
                    acc[mt][nt] = __builtin_amdgcn_mfma_f32_16x16x32_bf16(
                        afrag[mt], bfrag[nt], acc[mt][nt], 0, 0, 0);
        }

        // ---- +b1, LN, GELU -> Hl (bf16) ----
#pragma unroll
        for (int mt = 0; mt < 4; mt++) {
            float s[4] = {0.f, 0.f, 0.f, 0.f};
            float q[4] = {0.f, 0.f, 0.f, 0.f};
#pragma unroll
            for (int nt = 0; nt < 4; nt++) {
#pragma unroll
                for (int r = 0; r < 4; r++) {
                    float v = acc[mt][nt][r] + b1c[nt];
                    acc[mt][nt][r] = v;
                    s[r] += v;
                    q[r] += v * v;
                }
            }
#pragma unroll
            for (int m = 1; m < 16; m <<= 1) {
#pragma unroll
                for (int r = 0; r < 4; r++) {
                    s[r] += __shfl_xor(s[r], m);
                    q[r] += __shfl_xor(q[r], m);
                }
            }
#pragma unroll
            for (int r = 0; r < 4; r++) {
                float mu  = s[r] * (1.0f / 64.0f);
                float var = q[r] * (1.0f / 64.0f) - mu * mu;
                float inv = rsqrtf(var + 1e-5f);
                int row = mt * 16 + g * 4 + r;
#pragma unroll
                for (int nt = 0; nt < 4; nt++) {
                    float h = (acc[mt][nt][r] - mu) * inv * gc[nt] + bc[nt];
                    h = 0.5f * h * (1.0f + erff(h * 0.70710678118654752f));
                    Hl[row][col + 16 * nt] = f2bf(h);
                }
            }
        }
        // per-wave LDS region: no barrier needed (in-order DS per wave)

        // ---- GEMM2 ----
        f32x4 acc2[4][4];
#pragma unroll
        for (int mt = 0; mt < 4; mt++)
#pragma unroll
            for (int nt = 0; nt < 4; nt++)
                acc2[mt][nt] = (f32x4){0.f, 0.f, 0.f, 0.f};

#pragma unroll
        for (int ks = 0; ks < 2; ks++) {
            const int kk = ks * 32 + g * 8;
            short8 af[4], bf[4];
#pragma unroll
            for (int mt = 0; mt < 4; mt++)
                af[mt] = *(const short8*)&Hl[mt * 16 + col][kk];
#pragma unroll
            for (int nt = 0; nt < 4; nt++)
                bf[nt] = *(const short8*)(Wt2 + (size_t)(col + 16 * nt) * 64 + kk);
#pragma unroll
            for (int mt = 0; mt < 4; mt++)
#pragma unroll
                for (int nt = 0; nt < 4; nt++)
                    acc2[mt][nt] = __builtin_amdgcn_mfma_f32_16x16x32_bf16(
                        af[mt], bf[nt], acc2[mt][nt], 0, 0, 0);
        }

        // ---- run-reduced scatter over dst-sorted rows ----
        int cur = -1;
        float sum = 0.f;
#pragma unroll
        for (int p = 0; p < 2; p++) {
#pragma unroll
            for (int m2 = 0; m2 < 2; m2++) {
                int mt = 2 * p + m2;
#pragma unroll
                for (int nt = 0; nt < 4; nt++)
#pragma unroll
                    for (int r = 0; r < 4; r++)
                        Hf[m2 * 16 + g * 4 + r][col + 16 * nt] =
                            acc2[mt][nt][r] + b2c[nt];
            }
#pragma unroll 4
            for (int row = 0; row < 32; row++) {
                int d = dstL[p * 32 + row];
                float v = Hf[row][lane];
                if (d != cur) {
                    if (cur >= 0)
                        unsafeAtomicAdd(out + (size_t)cur * 64 + lane, sum);
                    cur = d; sum = 0.f;
                }
                if (d >= 0) sum += v;
            }
        }
        if (cur >= 0)
            unsafeAtomicAdd(out + (size_t)cur * 64 + lane, sum);
    }
#undef GBAR
}

// ======================= fallback kernels (round-2 path) ===================
__global__ void prep_weights(const float* __restrict__ W1,
                             const float* __restrict__ W2,
                             short* __restrict__ Wt1,
                             short* __restrict__ Wt2)
{
    int t = blockIdx.x * blockDim.x + threadIdx.x;
    if (t < 160 * 64) {
        int k = t / 64, n = t % 64;
        Wt1[n * 160 + k] = f2bf(W1[t]);
    }
    int t2 = t - 160 * 64;
    if (t2 >= 0 && t2 < 64 * 64) {
        int k = t2 / 64, n = t2 % 64;
        Wt2[n * 64 + k] = f2bf(W2[t2]);
    }
}

__global__ void prep_x_bf16(const float* __restrict__ x,
                            short* __restrict__ xbf,
                            int total8)
{
    int t = blockIdx.x * blockDim.x + threadIdx.x;
    if (t < total8) {
        const float4* xf4 = (const float4*)x;
        float4 a = xf4[2 * t];
        float4 b = xf4[2 * t + 1];
        ((short8*)xbf)[t] = pack8(a, b);
    }
}

__global__ void hist_dst(const int* __restrict__ ei, int* __restrict__ counts, int E)
{
    int e = blockIdx.x * blockDim.x + threadIdx.x;
    if (e < E) atomicAdd(&counts[ei[E + e]], 1);
}

#define SCAN_T 1024
__global__ __launch_bounds__(SCAN_T) void scan_offsets(const int* __restrict__ counts,
                                                       int* __restrict__ offs, int N)
{
    __shared__ int part[SCAN_T];
    int t = threadIdx.x;
    int chunk = (N + SCAN_T - 1) / SCAN_T;
    int lo = t * chunk, hi = min(lo + chunk, N);
    int s = 0;
    for (int i = lo; i < hi; i++) s += counts[i];
    part[t] = s;
    __syncthreads();
    for (int d = 1; d < SCAN_T; d <<= 1) {
        int v = (t >= d) ? part[t - d] : 0;
        __syncthreads();
        part[t] += v;
        __syncthreads();
    }
    int excl = (t == 0) ? 0 : part[t - 1];
    for (int i = lo; i < hi; i++) { int c = counts[i]; offs[i] = excl; excl += c; }
}

__global__ void build_perm(const int* __restrict__ ei, int* __restrict__ offs,
                           int* __restrict__ perm, int E)
{
    int e = blockIdx.x * blockDim.x + threadIdx.x;
    if (e < E) {
        int dst = ei[E + e];
        int pos = atomicAdd(&offs[dst], 1);
        perm[pos] = e;
    }
}

template <int MODE>
__global__ __launch_bounds__(256) void mpconv_mfma(
    const float* __restrict__ x,
    const short* __restrict__ xbf,
    const int*   __restrict__ ei,
    const float* __restrict__ ea,
    const short* __restrict__ Wt1,
    const float* __restrict__ b1,
    const float* __restrict__ gam,
    const float* __restrict__ bet,
    const short* __restrict__ Wt2,
    const float* __restrict__ b2,
    const int*   __restrict__ perm,
    float*       __restrict__ out,
    int E)
{
    __shared__ __align__(16) char smem[SMEM_BYTES];

    const int wave = threadIdx.x >> 6;
    const int lane = threadIdx.x & 63;
    const int g    = lane >> 4;
    const int col  = lane & 15;
    const int eb   = blockIdx.x * 256 + wave * 64;

    char* wbase = smem + wave * WREG;
    short (*Hl)[LDH] = (short (*)[LDH])wbase;
    float (*Hf)[66]  = (float (*)[66])wbase;
    int*  dstL       = (int*)(wbase + 9216);

    int aedge[4], ii[4], jj[4];
#pragma unroll
    for (int mt = 0; mt < 4; mt++) {
        int ep = eb + mt * 16 + col;
        bool v = (ep < E);
        int epc = v ? ep : (E - 1);
        int e = (MODE == 2) ? perm[epc] : epc;
        aedge[mt] = e;
        ii[mt] = ei[e];
        jj[mt] = ei[E + e];
        if (MODE == 2 && g == 0) dstL[mt * 16 + col] = v ? jj[mt] : -1;
    }

    float b1c[4], gc[4], bc[4], b2c[4];
#pragma unroll
    for (int nt = 0; nt < 4; nt++) {
        int c = col + 16 * nt;
        b1c[nt] = b1[c]; gc[nt] = gam[c]; bc[nt] = bet[c]; b2c[nt] = b2[c];
    }

    f32x4 acc[4][4];
#pragma unroll
    for (int mt = 0; mt < 4; mt++)
#pragma unroll
        for (int nt = 0; nt < 4; nt++)
            acc[mt][nt] = (f32x4){0.f, 0.f, 0.f, 0.f};

#pragma unroll
    for (int ks = 0; ks < 5; ks++) {
        const int k0 = ks * 32;
        const int kk = k0 + g * 8;

        short8 afrag[4];
#pragma unroll
        for (int mt = 0; mt < 4; mt++) {
            if (MODE >= 1 && k0 < 64) {
                afrag[mt] = *(const short8*)(xbf + (size_t)ii[mt] * 64 + kk);
            } else if (MODE >= 1 && k0 < 128) {
                afrag[mt] = *(const short8*)(xbf + (size_t)jj[mt] * 64 + (kk - 64));
            } else {
                const float* s;
                if (k0 < 64)       s = x  + (size_t)ii[mt] * 64 + kk;
                else if (k0 < 128) s = x  + (size_t)jj[mt] * 64 + (kk - 64);
                else               s = ea + (size_t)aedge[mt] * 32 + (kk - 128);
                float4 a = *(const float4*)s;
                float4 b = *(const float4*)(s + 4);
                afrag[mt] = pack8(a, b);
            }
        }
        short8 bfrag[4];
#pragma unroll
        for (int nt = 0; nt < 4; nt++)
            bfrag[nt] = *(const short8*)(Wt1 + (size_t)(col + 16 * nt) * 160 + kk);

#pragma unroll
        for (int mt = 0; mt < 4; mt++)
#pragma unroll
            for (int nt = 0; nt < 4; nt++)
                acc[mt][nt] = __builtin_amdgcn_mfma_f32_16x16x32_bf16(
                    afrag[mt], bfrag[nt], acc[mt][nt], 0, 0, 0);
    }

#pragma unroll
    for (int mt = 0; mt < 4; mt++) {
        float s[4] = {0.f, 0.f, 0.f, 0.f};
        float q[4] = {0.f, 0.f, 0.f, 0.f};
#pragma unroll
        for (int nt = 0; nt < 4; nt++) {
#pragma unroll
            for (int r = 0; r < 4; r++) {
                float v = acc[mt][nt][r] + b1c[nt];
                acc[mt][nt][r] = v;
                s[r] += v;
                q[r] += v * v;
            }
        }
#pragma unroll
        for (int m = 1; m < 16; m <<= 1) {
#pragma unroll
            for (int r = 0; r < 4; r++) {
                s[r] += __shfl_xor(s[r], m);
                q[r] += __shfl_xor(q[r], m);
            }
        }
#pragma unroll
        for (int r = 0; r < 4; r++) {
            float mu  = s[r] * (1.0f / 64.0f);
            float var = q[r] * (1.0f / 64.0f) - mu * mu;
            float inv = rsqrtf(var + 1e-5f);
            int row = mt * 16 + g * 4 + r;
#pragma unroll
            for (int nt = 0; nt < 4; nt++) {
                float h = (acc[mt][nt][r] - mu) * inv * gc[nt] + bc[nt];
                h = 0.5f * h * (1.0f + erff(h * 0.70710678118654752f));
                Hl[row][col + 16 * nt] = f2bf(h);
            }
        }
    }

    f32x4 acc2[4][4];
#pragma unroll
    for (int mt = 0; mt < 4; mt++)
#pragma unroll
        for (int nt = 0; nt < 4; nt++)
            acc2[mt][nt] = (f32x4){0.f, 0.f, 0.f, 0.f};

#pragma unroll
    for (int ks = 0; ks < 2; ks++) {
        const int kk = ks * 32 + g * 8;
        short8 af[4], bf[4];
#pragma unroll
        for (int mt = 0; mt < 4; mt++)
            af[mt] = *(const short8*)&Hl[mt * 16 + col][kk];
#pragma unroll
        for (int nt = 0; nt < 4; nt++)
            bf[nt] = *(const short8*)(Wt2 + (size_t)(col + 16 * nt) * 64 + kk);
#pragma unroll
        for (int mt = 0; mt < 4; mt++)
#pragma unroll
            for (int nt = 0; nt < 4; nt++)
                acc2[mt][nt] = __builtin_amdgcn_mfma_f32_16x16x32_bf16(
                    af[mt], bf[nt], acc2[mt][nt], 0, 0, 0);
    }

    if (MODE == 2) {
        int cur = -1;
        float sum = 0.f;
#pragma unroll
        for (int p = 0; p < 2; p++) {
#pragma unroll
            for (int m2 = 0; m2 < 2; m2++) {
                int mt = 2 * p + m2;
#pragma unroll
                for (int nt = 0; nt < 4; nt++)
#pragma unroll
                    for (int r = 0; r < 4; r++)
                        Hf[m2 * 16 + g * 4 + r][col + 16 * nt] =
                            acc2[mt][nt][r] + b2c[nt];
            }
#pragma unroll 4
            for (int row = 0; row < 32; row++) {
                int d = dstL[p * 32 + row];
                float v = Hf[row][lane];
                if (d != cur) {
                    if (cur >= 0)
                        unsafeAtomicAdd(out + (size_t)cur * 64 + lane, sum);
                    cur = d; sum = 0.f;
                }
                if (d >= 0) sum += v;
            }
        }
        if (cur >= 0)
            unsafeAtomicAdd(out + (size_t)cur * 64 + lane, sum);
    } else {
#pragma unroll
        for (int mt = 0; mt < 4; mt++) {
#pragma unroll
            for (int r = 0; r < 4; r++) {
                int e = eb + mt * 16 + g * 4 + r;
                if (e < E) {
                    int dst = ei[E + e];
                    float* op = out + (size_t)dst * 64 + col;
#pragma unroll
                    for (int nt = 0; nt < 4; nt++)
                        unsafeAtomicAdd(op + 16 * nt, acc2[mt][nt][r] + b2c[nt]);
                }
            }
        }
    }
}

// =========================== host launch ===================================
extern "C" void kernel_launch(void* const* d_in, const int* in_sizes, int n_in,
                              void* d_out, int out_size, void* d_ws, size_t ws_size,
                              hipStream_t stream)
{
    const float* x   = (const float*)d_in[0];
    const int*   ei  = (const int*)  d_in[1];
    const float* ea  = (const float*)d_in[2];
    const float* W1  = (const float*)d_in[3];
    const float* b1  = (const float*)d_in[4];
    const float* gam = (const float*)d_in[5];
    const float* bet = (const float*)d_in[6];
    const float* W2  = (const float*)d_in[7];
    const float* b2  = (const float*)d_in[8];
    float* out = (float*)d_out;

    const int E = in_sizes[1] / 2;
    const int N = in_sizes[0] / 64;

    // ws layout: Wt1 | Wt2 | xbf | counts | offs | perm | bsum | boff | cursor
    short* Wt1 = (short*)d_ws;
    short* Wt2 = Wt1 + 160 * 64;
    const size_t woff = (size_t)(160 * 64 + 64 * 64) * sizeof(short);   // 28,672
    short* xbf = (short*)((char*)d_ws + woff);
    const size_t need_xbf = woff + (size_t)N * 64 * sizeof(short);
    const size_t soff = (need_xbf + 255) & ~(size_t)255;
    int* counts = (int*)((char*)d_ws + soff);
    int* offs   = counts + N;
    int* perm   = offs + N;
    int* bsum   = perm + E;
    int* boff   = bsum + MAXBLK;
    int* cursor = boff + MAXBLK;
    const size_t need_sort = soff + (size_t)N * 8 + (size_t)E * 4;
    const size_t need_coop = need_sort + (size_t)MAXBLK * 8 + 256;

    // ---- cooperative single-kernel path ----
    static int s_nblk = 0;   // 0 = unknown, -1 = not viable
    if (s_nblk == 0) {
        int dev = 0;
        hipGetDevice(&dev);
        hipDeviceProp_t prop;
        hipError_t pe = hipGetDeviceProperties(&prop, dev);
        int bpc = 0;
        hipError_t oe = hipOccupancyMaxActiveBlocksPerMultiprocessor(
            &bpc, reinterpret_cast<const void*>(&mpconv_fused), 256, 0);
        if (pe == hipSuccess && oe == hipSuccess && bpc > 0 &&
            prop.cooperativeLaunch) {
            long cap = (long)bpc * prop.multiProcessorCount;
            s_nblk = (int)(cap > MAXBLK ? MAXBLK : cap);
            if (s_nblk < 8) s_nblk = -1;
        } else {
            s_nblk = -1;
        }
    }

    if (s_nblk > 0 && ws_size >= need_coop) {
        int Ev = E, Nv = N, Ov = out_size;
        void* args[] = {
            (void*)&x, (void*)&ei, (void*)&ea, (void*)&W1, (void*)&W2,
            (void*)&b1, (void*)&gam, (void*)&bet, (void*)&b2,
            (void*)&Wt1, (void*)&Wt2, (void*)&xbf,
            (void*)&counts, (void*)&offs, (void*)&bsum, (void*)&boff,
            (void*)&perm, (void*)&cursor, (void*)&out,
            (void*)&Ev, (void*)&Nv, (void*)&Ov
        };
        hipError_t le = hipLaunchCooperativeKernel(
            reinterpret_cast<const void*>(&mpconv_fused),
            dim3(s_nblk), dim3(256), args, 0, stream);
        if (le == hipSuccess) return;
        s_nblk = -1;   // don't retry next iteration
    }

    // ---- fallback: proven round-2 multi-kernel path ----
    const int mode = (ws_size >= need_sort) ? 2 : (ws_size >= need_xbf ? 1 : 0);

    hipMemsetAsync(d_out, 0, (size_t)out_size * sizeof(float), stream);
    {
        int total = 160 * 64 + 64 * 64;
        int grid = (total + 255) / 256;
        hipLaunchKernelGGL(prep_weights, dim3(grid), dim3(256), 0, stream,
                           W1, W2, Wt1, Wt2);
    }
    if (mode >= 1) {
        int total8 = N * 8;
        int grid = (total8 + 255) / 256;
        hipLaunchKernelGGL(prep_x_bf16, dim3(grid), dim3(256), 0, stream,
                           x, xbf, total8);
    }
    if (mode == 2) {
        hipMemsetAsync(counts, 0, (size_t)N * sizeof(int), stream);
        int gridE = (E + 255) / 256;
        hipLaunchKernelGGL(hist_dst, dim3(gridE), dim3(256), 0, stream,
                           ei, counts, E);
        hipLaunchKernelGGL(scan_offsets, dim3(1), dim3(SCAN_T), 0, stream,
                           counts, offs, N);
        hipLaunchKernelGGL(build_perm, dim3(gridE), dim3(256), 0, stream,
                           ei, offs, perm, E);
    }
    {
        int grid = (E + 255) / 256;
        if (mode == 2)
            hipLaunchKernelGGL(mpconv_mfma<2>, dim3(grid), dim3(256), 0, stream,
                               x, xbf, ei, ea, Wt1, b1, gam, bet, Wt2, b2, perm, out, E);
        else if (mode == 1)
            hipLaunchKernelGGL(mpconv_mfma<1>, dim3(grid), dim3(256), 0, stream,
                               x, xbf, ei, ea, Wt1, b1, gam, bet, Wt2, b2, perm, out, E);
        else
            hipLaunchKernelGGL(mpconv_mfma<0>, dim3(grid), dim3(256), 0, stream,
                               x, xbf, ei, ea, Wt1, b1, gam, bet, Wt2, b2, perm, out, E);
    }
}

// Round 4
// 1358.729 us; speedup vs baseline: 1.0122x; 1.0122x over previous
//
#include <hip/hip_runtime.h>
#include <hip/hip_cooperative_groups.h>
#include <math.h>

namespace cg = cooperative_groups;

// ---------------------------------------------------------------------------
// MPConv round 6: ONE cooperative kernel, STATIC chunked tile assignment.
// R3 lesson: a single global atomicAdd cursor serializes the whole grid at
// ~54 ns/claim (same-line device atomic across 8 XCDs) -> 1.35 ms floor.
// Static per-block chunks reproduce R2's proven 343us access pattern.
//   phase0: zero counts/out, prep W->bf16, x->bf16
//   phase1: hist(dst)   phase2a-c: parallel exclusive scan
//   phase3: build perm  phase4: main MPConv, static 256-edge tiles per block
// grid.sync() + __threadfence() between phases (cross-XCD visibility).
// Fallback on cooperative-launch error: round-2 multi-kernel sequence.
// ---------------------------------------------------------------------------

using short8 = __attribute__((ext_vector_type(8))) short;
using f32x4  = __attribute__((ext_vector_type(4))) float;

#define LDH 72        // bf16 H-tile stride (64+8)
#define WREG 9472     // per-wave LDS: max(64*72*2, 32*66*4)=9216 + 64*4 dstL, aligned
#define SMEM_BYTES (4 * WREG)   // 37,888
#define MAXBLK 4096

static __device__ __forceinline__ short f2bf(float f) {
    unsigned u = __float_as_uint(f);
    u += 0x7FFFu + ((u >> 16) & 1u);        // round-to-nearest-even
    return (short)(u >> 16);
}

static __device__ __forceinline__ short8 pack8(float4 a, float4 b) {
    short8 r;
    r[0] = f2bf(a.x); r[1] = f2bf(a.y); r[2] = f2bf(a.z); r[3] = f2bf(a.w);
    r[4] = f2bf(b.x); r[5] = f2bf(b.y); r[6] = f2bf(b.z); r[7] = f2bf(b.w);
    return r;
}

// ======================= fused cooperative kernel ==========================
__global__ __launch_bounds__(256) void mpconv_fused(
    const float* __restrict__ x,      // [N,64]
    const int*   __restrict__ ei,     // [2,E]
    const float* __restrict__ ea,     // [E,32]
    const float* __restrict__ W1,     // [160,64]
    const float* __restrict__ W2,     // [64,64]
    const float* __restrict__ b1,
    const float* __restrict__ gam,
    const float* __restrict__ bet,
    const float* __restrict__ b2,
    short* __restrict__ Wt1,          // [64][160] bf16
    short* __restrict__ Wt2,          // [64][64]  bf16
    short* __restrict__ xbf,          // [N][64]   bf16
    int*   __restrict__ counts,       // [N]
    int*   __restrict__ offs,         // [N]
    int*   __restrict__ bsum,         // [MAXBLK]
    int*   __restrict__ boff,         // [MAXBLK]
    int*   __restrict__ perm,         // [E]
    float* __restrict__ out,          // [N,64]
    int E, int N, int out_elems)
{
    __shared__ __align__(16) char smem[SMEM_BYTES];
    cg::grid_group grid = cg::this_grid();
    const int tid = blockIdx.x * 256 + threadIdx.x;
    const int TT  = gridDim.x * 256;

#define GBAR() do { __threadfence(); grid.sync(); __threadfence(); } while (0)

    // ---------------- phase 0: zero + weight/x prep ---------------------
    for (int i = tid; i < N; i += TT) counts[i] = 0;
    {
        int nf4 = out_elems >> 2;
        float4 z = make_float4(0.f, 0.f, 0.f, 0.f);
        for (int i = tid; i < nf4; i += TT) ((float4*)out)[i] = z;
        for (int i = (nf4 << 2) + tid; i < out_elems; i += TT) out[i] = 0.f;
    }
    for (int t = tid; t < 160 * 64; t += TT) {
        int k = t / 64, n = t % 64;
        Wt1[n * 160 + k] = f2bf(W1[t]);
    }
    for (int t = tid; t < 64 * 64; t += TT) {
        int k = t / 64, n = t % 64;
        Wt2[n * 64 + k] = f2bf(W2[t]);
    }
    {
        const float4* xf4 = (const float4*)x;
        for (int t = tid; t < N * 8; t += TT) {
            float4 a = xf4[2 * t];
            float4 b = xf4[2 * t + 1];
            ((short8*)xbf)[t] = pack8(a, b);
        }
    }
    GBAR();

    // ---------------- phase 1: histogram of dst -------------------------
    for (int e = tid; e < E; e += TT) atomicAdd(&counts[ei[E + e]], 1);
    GBAR();

    // ---------------- phase 2a: per-block chunk sums ---------------------
    const int NBLK = gridDim.x;
    const int CH = (N + NBLK - 1) / NBLK;
    int* sc = (int*)smem;
    {
        int base = blockIdx.x * CH;
        int s = 0;
        for (int o = threadIdx.x; o < CH; o += 256) {
            int i = base + o;
            if (i < N) s += counts[i];
        }
        sc[threadIdx.x] = s;
        __syncthreads();
        for (int d = 1; d < 256; d <<= 1) {
            int u = (threadIdx.x >= (unsigned)d) ? sc[threadIdx.x - d] : 0;
            __syncthreads();
            sc[threadIdx.x] += u;
            __syncthreads();
        }
        if (threadIdx.x == 255) bsum[blockIdx.x] = sc[255];
    }
    GBAR();

    // ---------------- phase 2b: block 0 scans bsum -> boff ---------------
    if (blockIdx.x == 0) {
        int per = (NBLK + 255) / 256;            // <= 16 (NBLK <= 4096)
        int lex[16];
        int lsum = 0;
#pragma unroll
        for (int i2 = 0; i2 < 16; i2++) {
            int idx = threadIdx.x * per + i2;
            int v = (i2 < per && idx < NBLK) ? bsum[idx] : 0;
            lex[i2] = lsum;
            lsum += v;
        }
        sc[threadIdx.x] = lsum;
        __syncthreads();
        for (int d = 1; d < 256; d <<= 1) {
            int u = (threadIdx.x >= (unsigned)d) ? sc[threadIdx.x - d] : 0;
            __syncthreads();
            sc[threadIdx.x] += u;
            __syncthreads();
        }
        int texcl = sc[threadIdx.x] - lsum;
#pragma unroll
        for (int i2 = 0; i2 < 16; i2++) {
            int idx = threadIdx.x * per + i2;
            if (i2 < per && idx < NBLK) boff[idx] = texcl + lex[i2];
        }
    }
    GBAR();

    // ---------------- phase 2c: exclusive offs within chunk --------------
    {
        int base = blockIdx.x * CH;
        int running = boff[blockIdx.x];
        for (int o = 0; o < CH; o += 256) {
            int li = o + (int)threadIdx.x;
            int i = base + li;
            int v = (li < CH && i < N) ? counts[i] : 0;
            sc[threadIdx.x] = v;
            __syncthreads();
            for (int d = 1; d < 256; d <<= 1) {
                int u = (threadIdx.x >= (unsigned)d) ? sc[threadIdx.x - d] : 0;
                __syncthreads();
                sc[threadIdx.x] += u;
                __syncthreads();
            }
            if (li < CH && i < N) offs[i] = running + sc[threadIdx.x] - v;
            running += sc[255];
            __syncthreads();
        }
    }
    GBAR();

    // ---------------- phase 3: build dst-sorted permutation --------------
    for (int e = tid; e < E; e += TT) {
        int dst = ei[E + e];
        int pos = atomicAdd(&offs[dst], 1);
        perm[pos] = e;
    }
    GBAR();

    // ---------------- phase 4: main MPConv, static chunked tiles ---------
    const int wave = threadIdx.x >> 6;
    const int lane = threadIdx.x & 63;
    const int g    = lane >> 4;
    const int col  = lane & 15;

    char* wbase = smem + wave * WREG;
    short (*Hl)[LDH] = (short (*)[LDH])wbase;   // [64][72] bf16
    float (*Hf)[66]  = (float (*)[66])wbase;    // [32][66] f32 (aliases Hl)
    int*  dstL       = (int*)(wbase + 9216);    // [64]

    float b1c[4], gc[4], bc[4], b2c[4];
#pragma unroll
    for (int nt = 0; nt < 4; nt++) {
        int c = col + 16 * nt;
        b1c[nt] = b1[c]; gc[nt] = gam[c]; bc[nt] = bet[c]; b2c[nt] = b2[c];
    }

    // balanced contiguous chunk of 256-edge tiles for this block
    const int ntiles = (E + 255) / 256;
    const int baseq  = ntiles / NBLK;
    const int rem    = ntiles % NBLK;
    const int myq    = baseq + (blockIdx.x < rem ? 1 : 0);
    const int t0     = (blockIdx.x < rem)
                         ? blockIdx.x * (baseq + 1)
                         : rem * (baseq + 1) + (blockIdx.x - rem) * baseq;

    for (int bt = t0; bt < t0 + myq; bt++) {
        const int eb = bt * 256 + wave * 64;

        int aedge[4], ii[4], jj[4];
#pragma unroll
        for (int mt = 0; mt < 4; mt++) {
            int ep = eb + mt * 16 + col;
            bool v = (ep < E);
            int epc = v ? ep : (E - 1);
            int e = perm[epc];
            aedge[mt] = e;
            ii[mt] = ei[e];
            jj[mt] = ei[E + e];
            if (g == 0) dstL[mt * 16 + col] = v ? jj[mt] : -1;
        }

        // ---- GEMM1 ----
        f32x4 acc[4][4];
#pragma unroll
        for (int mt = 0; mt < 4; mt++)
#pragma unroll
            for (int nt = 0; nt < 4; nt++)
                acc[mt][nt] = (f32x4){0.f, 0.f, 0.f, 0.f};

#pragma unroll
        for (int ks = 0; ks < 5; ks++) {
            const int k0 = ks * 32;
            const int kk = k0 + g * 8;

            short8 afrag[4];
#pragma unroll
            for (int mt = 0; mt < 4; mt++) {
                if (k0 < 64) {
                    afrag[mt] = *(const short8*)(xbf + (size_t)ii[mt] * 64 + kk);
                } else if (k0 < 128) {
                    afrag[mt] = *(const short8*)(xbf + (size_t)jj[mt] * 64 + (kk - 64));
                } else {
                    const float* s = ea + (size_t)aedge[mt] * 32 + (kk - 128);
                    float4 a = *(const float4*)s;
                    float4 b = *(const float4*)(s + 4);
                    afrag[mt] = pack8(a, b);
                }
            }
            short8 bfrag[4];
#pragma unroll
            for (int nt = 0; nt < 4; nt++)
                bfrag[nt] = *(const short8*)(Wt1 + (size_t)(col + 16 * nt) * 160 + kk);

#pragma unroll
            for (int mt = 0; mt < 4; mt++)
#pragma unroll
                for (int nt = 0; nt < 4; nt++)
                    acc[mt][nt] = __builtin_amdgcn_mfma_f32_16x16x32_bf16(
                        afrag[mt], bfrag[nt], acc[mt][nt], 0, 0, 0);
        }

        // ---- +b1, LN, GELU -> Hl (bf16) ----
#pragma unroll
        for (int mt = 0; mt < 4; mt++) {
            float s[4] = {0.f, 0.f, 0.f, 0.f};
            float q[4] = {0.f, 0.f, 0.f, 0.f};
#pragma unroll
            for (int nt = 0; nt < 4; nt++) {
#pragma unroll
                for (int r = 0; r < 4; r++) {
                    float v = acc[mt][nt][r] + b1c[nt];
                    acc[mt][nt][r] = v;
                    s[r] += v;
                    q[r] += v * v;
                }
            }
#pragma unroll
            for (int m = 1; m < 16; m <<= 1) {
#pragma unroll
                for (int r = 0; r < 4; r++) {
                    s[r] += __shfl_xor(s[r], m);
                    q[r] += __shfl_xor(q[r], m);
                }
            }
#pragma unroll
            for (int r = 0; r < 4; r++) {
                float mu  = s[r] * (1.0f / 64.0f);
                float var = q[r] * (1.0f / 64.0f) - mu * mu;
                float inv = rsqrtf(var + 1e-5f);
                int row = mt * 16 + g * 4 + r;
#pragma unroll
                for (int nt = 0; nt < 4; nt++) {
                    float h = (acc[mt][nt][r] - mu) * inv * gc[nt] + bc[nt];
                    h = 0.5f * h * (1.0f + erff(h * 0.70710678118654752f));
                    Hl[row][col + 16 * nt] = f2bf(h);
                }
            }
        }
        // per-wave LDS region: no barrier needed (in-order DS per wave)

        // ---- GEMM2 ----
        f32x4 acc2[4][4];
#pragma unroll
        for (int mt = 0; mt < 4; mt++)
#pragma unroll
            for (int nt = 0; nt < 4; nt++)
                acc2[mt][nt] = (f32x4){0.f, 0.f, 0.f, 0.f};

#pragma unroll
        for (int ks = 0; ks < 2; ks++) {
            const int kk = ks * 32 + g * 8;
            short8 af[4], bf[4];
#pragma unroll
            for (int mt = 0; mt < 4; mt++)
                af[mt] = *(const short8*)&Hl[mt * 16 + col][kk];
#pragma unroll
            for (int nt = 0; nt < 4; nt++)
                bf[nt] = *(const short8*)(Wt2 + (size_t)(col + 16 * nt) * 64 + kk);
#pragma unroll
            for (int mt = 0; mt < 4; mt++)
#pragma unroll
                for (int nt = 0; nt < 4; nt++)
                    acc2[mt][nt] = __builtin_amdgcn_mfma_f32_16x16x32_bf16(
                        af[mt], bf[nt], acc2[mt][nt], 0, 0, 0);
        }

        // ---- run-reduced scatter over dst-sorted rows ----
        int cur = -1;
        float sum = 0.f;
#pragma unroll
        for (int p = 0; p < 2; p++) {
#pragma unroll
            for (int m2 = 0; m2 < 2; m2++) {
                int mt = 2 * p + m2;
#pragma unroll
                for (int nt = 0; nt < 4; nt++)
#pragma unroll
                    for (int r = 0; r < 4; r++)
                        Hf[m2 * 16 + g * 4 + r][col + 16 * nt] =
                            acc2[mt][nt][r] + b2c[nt];
            }
#pragma unroll 4
            for (int row = 0; row < 32; row++) {
                int d = dstL[p * 32 + row];
                float v = Hf[row][lane];
                if (d != cur) {
                    if (cur >= 0)
                        unsafeAtomicAdd(out + (size_t)cur * 64 + lane, sum);
                    cur = d; sum = 0.f;
                }
                if (d >= 0) sum += v;
            }
        }
        if (cur >= 0)
            unsafeAtomicAdd(out + (size_t)cur * 64 + lane, sum);
    }
#undef GBAR
}

// ======================= fallback kernels (round-2 path) ===================
__global__ void prep_weights(const float* __restrict__ W1,
                             const float* __restrict__ W2,
                             short* __restrict__ Wt1,
                             short* __restrict__ Wt2)
{
    int t = blockIdx.x * blockDim.x + threadIdx.x;
    if (t < 160 * 64) {
        int k = t / 64, n = t % 64;
        Wt1[n * 160 + k] = f2bf(W1[t]);
    }
    int t2 = t - 160 * 64;
    if (t2 >= 0 && t2 < 64 * 64) {
        int k = t2 / 64, n = t2 % 64;
        Wt2[n * 64 + k] = f2bf(W2[t2]);
    }
}

__global__ void prep_x_bf16(const float* __restrict__ x,
                            short* __restrict__ xbf,
                            int total8)
{
    int t = blockIdx.x * blockDim.x + threadIdx.x;
    if (t < total8) {
        const float4* xf4 = (const float4*)x;
        float4 a = xf4[2 * t];
        float4 b = xf4[2 * t + 1];
        ((short8*)xbf)[t] = pack8(a, b);
    }
}

__global__ void hist_dst(const int* __restrict__ ei, int* __restrict__ counts, int E)
{
    int e = blockIdx.x * blockDim.x + threadIdx.x;
    if (e < E) atomicAdd(&counts[ei[E + e]], 1);
}

#define SCAN_T 1024
__global__ __launch_bounds__(SCAN_T) void scan_offsets(const int* __restrict__ counts,
                                                       int* __restrict__ offs, int N)
{
    __shared__ int part[SCAN_T];
    int t = threadIdx.x;
    int chunk = (N + SCAN_T - 1) / SCAN_T;
    int lo = t * chunk, hi = min(lo + chunk, N);
    int s = 0;
    for (int i = lo; i < hi; i++) s += counts[i];
    part[t] = s;
    __syncthreads();
    for (int d = 1; d < SCAN_T; d <<= 1) {
        int v = (t >= d) ? part[t - d] : 0;
        __syncthreads();
        part[t] += v;
        __syncthreads();
    }
    int excl = (t == 0) ? 0 : part[t - 1];
    for (int i = lo; i < hi; i++) { int c = counts[i]; offs[i] = excl; excl += c; }
}

__global__ void build_perm(const int* __restrict__ ei, int* __restrict__ offs,
                           int* __restrict__ perm, int E)
{
    int e = blockIdx.x * blockDim.x + threadIdx.x;
    if (e < E) {
        int dst = ei[E + e];
        int pos = atomicAdd(&offs[dst], 1);
        perm[pos] = e;
    }
}

template <int MODE>
__global__ __launch_bounds__(256) void mpconv_mfma(
    const float* __restrict__ x,
    const short* __restrict__ xbf,
    const int*   __restrict__ ei,
    const float* __restrict__ ea,
    const short* __restrict__ Wt1,
    const float* __restrict__ b1,
    const float* __restrict__ gam,
    const float* __restrict__ bet,
    const short* __restrict__ Wt2,
    const float* __restrict__ b2,
    const int*   __restrict__ perm,
    float*       __restrict__ out,
    int E)
{
    __shared__ __align__(16) char smem[SMEM_BYTES];

    const int wave = threadIdx.x >> 6;
    const int lane = threadIdx.x & 63;
    const int g    = lane >> 4;
    const int col  = lane & 15;
    const int eb   = blockIdx.x * 256 + wave * 64;

    char* wbase = smem + wave * WREG;
    short (*Hl)[LDH] = (short (*)[LDH])wbase;
    float (*Hf)[66]  = (float (*)[66])wbase;
    int*  dstL       = (int*)(wbase + 9216);

    int aedge[4], ii[4], jj[4];
#pragma unroll
    for (int mt = 0; mt < 4; mt++) {
        int ep = eb + mt * 16 + col;
        bool v = (ep < E);
        int epc = v ? ep : (E - 1);
        int e = (MODE == 2) ? perm[epc] : epc;
        aedge[mt] = e;
        ii[mt] = ei[e];
        jj[mt] = ei[E + e];
        if (MODE == 2 && g == 0) dstL[mt * 16 + col] = v ? jj[mt] : -1;
    }

    float b1c[4], gc[4], bc[4], b2c[4];
#pragma unroll
    for (int nt = 0; nt < 4; nt++) {
        int c = col + 16 * nt;
        b1c[nt] = b1[c]; gc[nt] = gam[c]; bc[nt] = bet[c]; b2c[nt] = b2[c];
    }

    f32x4 acc[4][4];
#pragma unroll
    for (int mt = 0; mt < 4; mt++)
#pragma unroll
        for (int nt = 0; nt < 4; nt++)
            acc[mt][nt] = (f32x4){0.f, 0.f, 0.f, 0.f};

#pragma unroll
    for (int ks = 0; ks < 5; ks++) {
        const int k0 = ks * 32;
        const int kk = k0 + g * 8;

        short8 afrag[4];
#pragma unroll
        for (int mt = 0; mt < 4; mt++) {
            if (MODE >= 1 && k0 < 64) {
                afrag[mt] = *(const short8*)(xbf + (size_t)ii[mt] * 64 + kk);
            } else if (MODE >= 1 && k0 < 128) {
                afrag[mt] = *(const short8*)(xbf + (size_t)jj[mt] * 64 + (kk - 64));
            } else {
                const float* s;
                if (k0 < 64)       s = x  + (size_t)ii[mt] * 64 + kk;
                else if (k0 < 128) s = x  + (size_t)jj[mt] * 64 + (kk - 64);
                else               s = ea + (size_t)aedge[mt] * 32 + (kk - 128);
                float4 a = *(const float4*)s;
                float4 b = *(const float4*)(s + 4);
                afrag[mt] = pack8(a, b);
            }
        }
        short8 bfrag[4];
#pragma unroll
        for (int nt = 0; nt < 4; nt++)
            bfrag[nt] = *(const short8*)(Wt1 + (size_t)(col + 16 * nt) * 160 + kk);

#pragma unroll
        for (int mt = 0; mt < 4; mt++)
#pragma unroll
            for (int nt = 0; nt < 4; nt++)
                acc[mt][nt] = __builtin_amdgcn_mfma_f32_16x16x32_bf16(
                    afrag[mt], bfrag[nt], acc[mt][nt], 0, 0, 0);
    }

#pragma unroll
    for (int mt = 0; mt < 4; mt++) {
        float s[4] = {0.f, 0.f, 0.f, 0.f};
        float q[4] = {0.f, 0.f, 0.f, 0.f};
#pragma unroll
        for (int nt = 0; nt < 4; nt++) {
#pragma unroll
            for (int r = 0; r < 4; r++) {
                float v = acc[mt][nt][r] + b1c[nt];
                acc[mt][nt][r] = v;
                s[r] += v;
                q[r] += v * v;
            }
        }
#pragma unroll
        for (int m = 1; m < 16; m <<= 1) {
#pragma unroll
            for (int r = 0; r < 4; r++) {
                s[r] += __shfl_xor(s[r], m);
                q[r] += __shfl_xor(q[r], m);
            }
        }
#pragma unroll
        for (int r = 0; r < 4; r++) {
            float mu  = s[r] * (1.0f / 64.0f);
            float var = q[r] * (1.0f / 64.0f) - mu * mu;
            float inv = rsqrtf(var + 1e-5f);
            int row = mt * 16 + g * 4 + r;
#pragma unroll
            for (int nt = 0; nt < 4; nt++) {
                float h = (acc[mt][nt][r] - mu) * inv * gc[nt] + bc[nt];
                h = 0.5f * h * (1.0f + erff(h * 0.70710678118654752f));
                Hl[row][col + 16 * nt] = f2bf(h);
            }
        }
    }

    f32x4 acc2[4][4];
#pragma unroll
    for (int mt = 0; mt < 4; mt++)
#pragma unroll
        for (int nt = 0; nt < 4; nt++)
            acc2[mt][nt] = (f32x4){0.f, 0.f, 0.f, 0.f};

#pragma unroll
    for (int ks = 0; ks < 2; ks++) {
        const int kk = ks * 32 + g * 8;
        short8 af[4], bf[4];
#pragma unroll
        for (int mt = 0; mt < 4; mt++)
            af[mt] = *(const short8*)&Hl[mt * 16 + col][kk];
#pragma unroll
        for (int nt = 0; nt < 4; nt++)
            bf[nt] = *(const short8*)(Wt2 + (size_t)(col + 16 * nt) * 64 + kk);
#pragma unroll
        for (int mt = 0; mt < 4; mt++)
#pragma unroll
            for (int nt = 0; nt < 4; nt++)
                acc2[mt][nt] = __builtin_amdgcn_mfma_f32_16x16x32_bf16(
                    af[mt], bf[nt], acc2[mt][nt], 0, 0, 0);
    }

    if (MODE == 2) {
        int cur = -1;
        float sum = 0.f;
#pragma unroll
        for (int p = 0; p < 2; p++) {
#pragma unroll
            for (int m2 = 0; m2 < 2; m2++) {
                int mt = 2 * p + m2;
#pragma unroll
                for (int nt = 0; nt < 4; nt++)
#pragma unroll
                    for (int r = 0; r < 4; r++)
                        Hf[m2 * 16 + g * 4 + r][col + 16 * nt] =
                            acc2[mt][nt][r] + b2c[nt];
            }
#pragma unroll 4
            for (int row = 0; row < 32; row++) {
                int d = dstL[p * 32 + row];
                float v = Hf[row][lane];
                if (d != cur) {
                    if (cur >= 0)
                        unsafeAtomicAdd(out + (size_t)cur * 64 + lane, sum);
                    cur = d; sum = 0.f;
                }
                if (d >= 0) sum += v;
            }
        }
        if (cur >= 0)
            unsafeAtomicAdd(out + (size_t)cur * 64 + lane, sum);
    } else {
#pragma unroll
        for (int mt = 0; mt < 4; mt++) {
#pragma unroll
            for (int r = 0; r < 4; r++) {
                int e = eb + mt * 16 + g * 4 + r;
                if (e < E) {
                    int dst = ei[E + e];
                    float* op = out + (size_t)dst * 64 + col;
#pragma unroll
                    for (int nt = 0; nt < 4; nt++)
                        unsafeAtomicAdd(op + 16 * nt, acc2[mt][nt][r] + b2c[nt]);
                }
            }
        }
    }
}

// =========================== host launch ===================================
extern "C" void kernel_launch(void* const* d_in, const int* in_sizes, int n_in,
                              void* d_out, int out_size, void* d_ws, size_t ws_size,
                              hipStream_t stream)
{
    const float* x   = (const float*)d_in[0];
    const int*   ei  = (const int*)  d_in[1];
    const float* ea  = (const float*)d_in[2];
    const float* W1  = (const float*)d_in[3];
    const float* b1  = (const float*)d_in[4];
    const float* gam = (const float*)d_in[5];
    const float* bet = (const float*)d_in[6];
    const float* W2  = (const float*)d_in[7];
    const float* b2  = (const float*)d_in[8];
    float* out = (float*)d_out;

    const int E = in_sizes[1] / 2;
    const int N = in_sizes[0] / 64;

    // ws layout: Wt1 | Wt2 | xbf | counts | offs | perm | bsum | boff
    short* Wt1 = (short*)d_ws;
    short* Wt2 = Wt1 + 160 * 64;
    const size_t woff = (size_t)(160 * 64 + 64 * 64) * sizeof(short);   // 28,672
    short* xbf = (short*)((char*)d_ws + woff);
    const size_t need_xbf = woff + (size_t)N * 64 * sizeof(short);
    const size_t soff = (need_xbf + 255) & ~(size_t)255;
    int* counts = (int*)((char*)d_ws + soff);
    int* offs   = counts + N;
    int* perm   = offs + N;
    int* bsum   = perm + E;
    int* boff   = bsum + MAXBLK;
    const size_t need_sort = soff + (size_t)N * 8 + (size_t)E * 4;
    const size_t need_coop = need_sort + (size_t)MAXBLK * 8 + 256;

    // ---- cooperative single-kernel path ----
    static int s_nblk = 0;   // 0 = unknown, -1 = not viable
    if (s_nblk == 0) {
        int dev = 0;
        hipGetDevice(&dev);
        hipDeviceProp_t prop;
        hipError_t pe = hipGetDeviceProperties(&prop, dev);
        int bpc = 0;
        hipError_t oe = hipOccupancyMaxActiveBlocksPerMultiprocessor(
            &bpc, reinterpret_cast<const void*>(&mpconv_fused), 256, 0);
        if (pe == hipSuccess && oe == hipSuccess && bpc > 0 &&
            prop.cooperativeLaunch) {
            long cap = (long)bpc * prop.multiProcessorCount;
            s_nblk = (int)(cap > MAXBLK ? MAXBLK : cap);
            if (s_nblk < 8) s_nblk = -1;
        } else {
            s_nblk = -1;
        }
    }

    if (s_nblk > 0 && ws_size >= need_coop) {
        int Ev = E, Nv = N, Ov = out_size;
        void* args[] = {
            (void*)&x, (void*)&ei, (void*)&ea, (void*)&W1, (void*)&W2,
            (void*)&b1, (void*)&gam, (void*)&bet, (void*)&b2,
            (void*)&Wt1, (void*)&Wt2, (void*)&xbf,
            (void*)&counts, (void*)&offs, (void*)&bsum, (void*)&boff,
            (void*)&perm, (void*)&out,
            (void*)&Ev, (void*)&Nv, (void*)&Ov
        };
        hipError_t le = hipLaunchCooperativeKernel(
            reinterpret_cast<const void*>(&mpconv_fused),
            dim3(s_nblk), dim3(256), args, 0, stream);
        if (le == hipSuccess) return;
        s_nblk = -1;   // don't retry next iteration
    }

    // ---- fallback: proven round-2 multi-kernel path ----
    const int mode = (ws_size >= need_sort) ? 2 : (ws_size >= need_xbf ? 1 : 0);

    hipMemsetAsync(d_out, 0, (size_t)out_size * sizeof(float), stream);
    {
        int total = 160 * 64 + 64 * 64;
        int grid = (total + 255) / 256;
        hipLaunchKernelGGL(prep_weights, dim3(grid), dim3(256), 0, stream,
                           W1, W2, Wt1, Wt2);
    }
    if (mode >= 1) {
        int total8 = N * 8;
        int grid = (total8 + 255) / 256;
        hipLaunchKernelGGL(prep_x_bf16, dim3(grid), dim3(256), 0, stream,
                           x, xbf, total8);
    }
    if (mode == 2) {
        hipMemsetAsync(counts, 0, (size_t)N * sizeof(int), stream);
        int gridE = (E + 255) / 256;
        hipLaunchKernelGGL(hist_dst, dim3(gridE), dim3(256), 0, stream,
                           ei, counts, E);
        hipLaunchKernelGGL(scan_offsets, dim3(1), dim3(SCAN_T), 0, stream,
                           counts, offs, N);
        hipLaunchKernelGGL(build_perm, dim3(gridE), dim3(256), 0, stream,
                           ei, offs, perm, E);
    }
    {
        int grid = (E + 255) / 256;
        if (mode == 2)
            hipLaunchKernelGGL(mpconv_mfma<2>, dim3(grid), dim3(256), 0, stream,
                               x, xbf, ei, ea, Wt1, b1, gam, bet, Wt2, b2, perm, out, E);
        else if (mode == 1)
            hipLaunchKernelGGL(mpconv_mfma<1>, dim3(grid), dim3(256), 0, stream,
                               x, xbf, ei, ea, Wt1, b1, gam, bet, Wt2, b2, perm, out, E);
        else
            hipLaunchKernelGGL(mpconv_mfma<0>, dim3(grid), dim3(256), 0, stream,
                               x, xbf, ei, ea, Wt1, b1, gam, bet, Wt2, b2, perm, out, E);
    }
}

// Round 6
// 692.905 us; speedup vs baseline: 1.9848x; 1.9609x over previous
//
#include <hip/hip_runtime.h>
#include <math.h>

// ---------------------------------------------------------------------------
// MPConv round 8: TWO launches, scalar atomics (pk_add_f32 doesn't exist on
// gfx950 — R5 build proved it). Frame: minimize launch count (~65us/gap).
//   launch 1: prep_all  (zero out + W1/W2 -> bf16 transposed + x -> bf16)
//   launch 2: mpconv    (R1-proven main: GEMM1 -> LN+GELU -> GEMM2 ->
//                        direct unsafeAtomicAdd scatter, 64 f32 adds/edge)
// ---------------------------------------------------------------------------

using short8 = __attribute__((ext_vector_type(8))) short;
using f32x4  = __attribute__((ext_vector_type(4))) float;

#define LDH 72   // LDS stride for H tile, in bf16 elements (64+8 pad)

static __device__ __forceinline__ short f2bf(float f) {
    unsigned u = __float_as_uint(f);
    u += 0x7FFFu + ((u >> 16) & 1u);        // round-to-nearest-even
    return (short)(u >> 16);
}

static __device__ __forceinline__ short8 pack8(float4 a, float4 b) {
    short8 r;
    r[0] = f2bf(a.x); r[1] = f2bf(a.y); r[2] = f2bf(a.z); r[3] = f2bf(a.w);
    r[4] = f2bf(b.x); r[5] = f2bf(b.y); r[6] = f2bf(b.z); r[7] = f2bf(b.w);
    return r;
}

// ---- single prep kernel: zero out + weights -> bf16 [n][k] + x -> bf16 ----
__global__ __launch_bounds__(256) void prep_all(
    const float* __restrict__ x,      // [N,64]
    const float* __restrict__ W1,     // [160,64]
    const float* __restrict__ W2,     // [64,64]
    short* __restrict__ Wt1,          // [64][160]
    short* __restrict__ Wt2,          // [64][64]
    short* __restrict__ xbf,          // [N][64]
    float* __restrict__ out,
    int N, int out_elems, int doX)
{
    const int tid = blockIdx.x * 256 + threadIdx.x;
    const int TT  = gridDim.x * 256;

    // zero the output (atomics accumulate into it)
    const int nf4 = out_elems >> 2;
    const float4 z = make_float4(0.f, 0.f, 0.f, 0.f);
    for (int i = tid; i < nf4; i += TT) ((float4*)out)[i] = z;
    for (int i = (nf4 << 2) + tid; i < out_elems; i += TT) out[i] = 0.f;

    // W1 [k][n] -> Wt1 [n][k]
    for (int t = tid; t < 160 * 64; t += TT) {
        int k = t / 64, n = t % 64;
        Wt1[n * 160 + k] = f2bf(W1[t]);
    }
    // W2 [k][n] -> Wt2 [n][k]
    for (int t = tid; t < 64 * 64; t += TT) {
        int k = t / 64, n = t % 64;
        Wt2[n * 64 + k] = f2bf(W2[t]);
    }
    // x f32 -> bf16, 8 elems/thread
    if (doX) {
        const float4* xf4 = (const float4*)x;
        for (int t = tid; t < N * 8; t += TT) {
            float4 a = xf4[2 * t];
            float4 b = xf4[2 * t + 1];
            ((short8*)xbf)[t] = pack8(a, b);
        }
    }
}

// ---- main kernel: 4 waves x 64 edges, direct atomic scatter ---------------
template <bool XBF>
__global__ __launch_bounds__(256) void mpconv_mfma(
    const float* __restrict__ x,      // [N,64]
    const short* __restrict__ xbf,    // [N][64] bf16 (valid iff XBF)
    const int*   __restrict__ ei,     // [2,E]
    const float* __restrict__ ea,     // [E,32]
    const short* __restrict__ Wt1,    // [64][160] bf16
    const float* __restrict__ b1,
    const float* __restrict__ gam,
    const float* __restrict__ bet,
    const short* __restrict__ Wt2,    // [64][64] bf16
    const float* __restrict__ b2,
    float*       __restrict__ out,    // [N,64]
    int E)
{
    __shared__ __align__(16) short Hlds[4][64][LDH];   // 36,864 B

    const int wave = threadIdx.x >> 6;
    const int lane = threadIdx.x & 63;
    const int g    = lane >> 4;        // quad id 0..3
    const int col  = lane & 15;
    const int eb   = blockIdx.x * 256 + wave * 64;     // wave's edge base

    // edges whose A-rows this lane loads (row m = col in each 16-row M tile)
    int aedge[4], ii[4], jj[4];
#pragma unroll
    for (int mt = 0; mt < 4; mt++) {
        int e = eb + mt * 16 + col;
        e = (e < E) ? e : (E - 1);     // clamp; invalid rows skipped at scatter
        aedge[mt] = e;
        ii[mt] = ei[e];
        jj[mt] = ei[E + e];
    }

    // per-lane channel params for its 4 columns (col + 16*nt)
    float b1c[4], gc[4], bc[4], b2c[4];
#pragma unroll
    for (int nt = 0; nt < 4; nt++) {
        int c = col + 16 * nt;
        b1c[nt] = b1[c]; gc[nt] = gam[c]; bc[nt] = bet[c]; b2c[nt] = b2[c];
    }

    // ---- GEMM1: [64,160] @ [160,64] -----------------------------------
    f32x4 acc[4][4];
#pragma unroll
    for (int mt = 0; mt < 4; mt++)
#pragma unroll
        for (int nt = 0; nt < 4; nt++)
            acc[mt][nt] = (f32x4){0.f, 0.f, 0.f, 0.f};

#pragma unroll
    for (int ks = 0; ks < 5; ks++) {
        const int k0 = ks * 32;
        const int kk = k0 + g * 8;     // this quad's k-chunk (8 wide)

        short8 afrag[4];
#pragma unroll
        for (int mt = 0; mt < 4; mt++) {
            if (XBF && k0 < 64) {
                afrag[mt] = *(const short8*)(xbf + (size_t)ii[mt] * 64 + kk);
            } else if (XBF && k0 < 128) {
                afrag[mt] = *(const short8*)(xbf + (size_t)jj[mt] * 64 + (kk - 64));
            } else {
                const float* s;
                if (k0 < 64)       s = x  + (size_t)ii[mt] * 64 + kk;
                else if (k0 < 128) s = x  + (size_t)jj[mt] * 64 + (kk - 64);
                else               s = ea + (size_t)aedge[mt] * 32 + (kk - 128);
                float4 a = *(const float4*)s;
                float4 b = *(const float4*)(s + 4);
                afrag[mt] = pack8(a, b);
            }
        }
        short8 bfrag[4];
#pragma unroll
        for (int nt = 0; nt < 4; nt++)
            bfrag[nt] = *(const short8*)(Wt1 + (size_t)(col + 16 * nt) * 160 + kk);

#pragma unroll
        for (int mt = 0; mt < 4; mt++)
#pragma unroll
            for (int nt = 0; nt < 4; nt++)
                acc[mt][nt] = __builtin_amdgcn_mfma_f32_16x16x32_bf16(
                    afrag[mt], bfrag[nt], acc[mt][nt], 0, 0, 0);
    }

    // ---- +b1, LayerNorm, GELU, write H to LDS -------------------------
    // C layout: row = g*4 + r, col = col + 16*nt  (within each 16x16 tile)
#pragma unroll
    for (int mt = 0; mt < 4; mt++) {
        float s[4] = {0.f, 0.f, 0.f, 0.f};
        float q[4] = {0.f, 0.f, 0.f, 0.f};
#pragma unroll
        for (int nt = 0; nt < 4; nt++) {
#pragma unroll
            for (int r = 0; r < 4; r++) {
                float v = acc[mt][nt][r] + b1c[nt];
                acc[mt][nt][r] = v;
                s[r] += v;
                q[r] += v * v;
            }
        }
#pragma unroll
        for (int m = 1; m < 16; m <<= 1) {
#pragma unroll
            for (int r = 0; r < 4; r++) {
                s[r] += __shfl_xor(s[r], m);
                q[r] += __shfl_xor(q[r], m);
            }
        }
#pragma unroll
        for (int r = 0; r < 4; r++) {
            float mu  = s[r] * (1.0f / 64.0f);
            float var = q[r] * (1.0f / 64.0f) - mu * mu;
            float inv = rsqrtf(var + 1e-5f);
            int row = mt * 16 + g * 4 + r;
#pragma unroll
            for (int nt = 0; nt < 4; nt++) {
                float h = (acc[mt][nt][r] - mu) * inv * gc[nt] + bc[nt];
                h = 0.5f * h * (1.0f + erff(h * 0.70710678118654752f));
                Hlds[wave][row][col + 16 * nt] = f2bf(h);
            }
        }
    }
    __syncthreads();

    // ---- GEMM2: [64,64] @ [64,64] -------------------------------------
    f32x4 acc2[4][4];
#pragma unroll
    for (int mt = 0; mt < 4; mt++)
#pragma unroll
        for (int nt = 0; nt < 4; nt++)
            acc2[mt][nt] = (f32x4){0.f, 0.f, 0.f, 0.f};

#pragma unroll
    for (int ks = 0; ks < 2; ks++) {
        const int kk = ks * 32 + g * 8;
        short8 af[4], bf[4];
#pragma unroll
        for (int mt = 0; mt < 4; mt++)
            af[mt] = *(const short8*)&Hlds[wave][mt * 16 + col][kk];
#pragma unroll
        for (int nt = 0; nt < 4; nt++)
            bf[nt] = *(const short8*)(Wt2 + (size_t)(col + 16 * nt) * 64 + kk);
#pragma unroll
        for (int mt = 0; mt < 4; mt++)
#pragma unroll
            for (int nt = 0; nt < 4; nt++)
                acc2[mt][nt] = __builtin_amdgcn_mfma_f32_16x16x32_bf16(
                    af[mt], bf[nt], acc2[mt][nt], 0, 0, 0);
    }

    // ---- +b2 and scatter-add to out[j] --------------------------------
#pragma unroll
    for (int mt = 0; mt < 4; mt++) {
#pragma unroll
        for (int r = 0; r < 4; r++) {
            int e = eb + mt * 16 + g * 4 + r;
            if (e < E) {
                int dst = ei[E + e];           // wave-uniform per 16-lane group
                float* op = out + (size_t)dst * 64 + col;
#pragma unroll
                for (int nt = 0; nt < 4; nt++)
                    unsafeAtomicAdd(op + 16 * nt, acc2[mt][nt][r] + b2c[nt]);
            }
        }
    }
}

// =========================== host launch ===================================
extern "C" void kernel_launch(void* const* d_in, const int* in_sizes, int n_in,
                              void* d_out, int out_size, void* d_ws, size_t ws_size,
                              hipStream_t stream)
{
    const float* x   = (const float*)d_in[0];
    const int*   ei  = (const int*)  d_in[1];
    const float* ea  = (const float*)d_in[2];
    const float* W1  = (const float*)d_in[3];
    const float* b1  = (const float*)d_in[4];
    const float* gam = (const float*)d_in[5];
    const float* bet = (const float*)d_in[6];
    const float* W2  = (const float*)d_in[7];
    const float* b2  = (const float*)d_in[8];
    float* out = (float*)d_out;

    const int E = in_sizes[1] / 2;
    const int N = in_sizes[0] / 64;

    // workspace: Wt1 bf16 [64][160] | Wt2 bf16 [64][64] | xbf bf16 [N][64]
    short* Wt1 = (short*)d_ws;
    short* Wt2 = Wt1 + 160 * 64;
    const size_t woff = (size_t)(160 * 64 + 64 * 64) * sizeof(short);  // 28,672
    short* xbf = (short*)((char*)d_ws + woff);
    const size_t need_xbf = woff + (size_t)N * 64 * sizeof(short);
    const int use_xbf = (ws_size >= need_xbf) ? 1 : 0;

    // launch 1: fused prep (zero + W->bf16 + x->bf16)
    hipLaunchKernelGGL(prep_all, dim3(1024), dim3(256), 0, stream,
                       x, W1, W2, Wt1, Wt2, xbf, out, N, out_size, use_xbf);

    // launch 2: main
    {
        int grid = (E + 255) / 256;
        if (use_xbf)
            hipLaunchKernelGGL(mpconv_mfma<true>, dim3(grid), dim3(256), 0, stream,
                               x, xbf, ei, ea, Wt1, b1, gam, bet, Wt2, b2, out, E);
        else
            hipLaunchKernelGGL(mpconv_mfma<false>, dim3(grid), dim3(256), 0, stream,
                               x, xbf, ei, ea, Wt1, b1, gam, bet, Wt2, b2, out, E);
    }
}